// Round 15
// baseline (259.964 us; speedup 1.0000x reference)
//
#include <hip/hip_runtime.h>
#include <cmath>

// PhaseAwareClassifier on MI355X — R32: R30 + 9-wave 2-round packing +
// chunk-17 elimination.
// R31 post-mortem: conn register cache DEAD — compiler silently
// rematerializes LDS-sourced "cached" values (VGPR 228 < 288 needed, no
// spill, no hold) and 1 wave/SIMD re-exposed latency (3rd confirmation:
// R22/R28/R31 all lose 25-40% at 1/SIMD). Reverted to R30's body.
// R30's waste was PACKING: 3 rounds x 52.6us with round 3 carrying only
// 128/4224 tasks (16/256 blocks). R32: 9-wave blocks (576 thr) -> 2304
// workers -> exactly 2 rounds (2304 + 1920, tail 83% loaded).
// LDS fit via chunk-17 elimination: conn chunk 17 is identically zero
// (k>=131) and OB chunk 17 (out rows 136..143) is provably exact zero
// (conn rows >=131 zero, inj<49, 0*finite=0 in epilogue). Store 17 chunks;
// kt4 quads 1..3 use register zeros (identical operand values -> bit-exact;
// kt4 loads become quad0-only, exec-masked -> less LDS traffic).
// LDS: 2x39,168 (conn) + 78,336 (OBP 9 waves x 17ch) + 576 = 157,248 B.
// Per-acc MFMA chain order kt-ascending unchanged (absmax 0.0078125).

#define NSTEPS  10
#define INJ_ST  4
#define MT      144          // padded M (9 tiles of 16)
#define NTASK   4224         // 33 unique l x 128 images

typedef __bf16 bf16x8 __attribute__((ext_vector_type(8)));
typedef __bf16 bf16x4 __attribute__((ext_vector_type(4)));
typedef short  short8 __attribute__((ext_vector_type(8)));
typedef float  f32x4  __attribute__((ext_vector_type(4)));

// workspace layout (float offsets)
#define WS_MAX    0          // 1      enc_max (uint-ordered float)
#define WS_ENERGY 64         // 1280   energy[b][10]
#define WS_GSP    2048       // 144    g2q[j] = -0.5*log2(e)*softplus(gain)
#define WS_CONN   4096       // 2 bf16 mats [20][144][8] chunked: Cr, Ci

// fused prep: blocks 0..97 = image absmax; blocks 98.. = conn + gsp tables
__global__ void k_pre(const float* __restrict__ img,
                      const float* __restrict__ cr, const float* __restrict__ ci,
                      const float* __restrict__ phase, const float* __restrict__ gain,
                      float* ws) {
    if (blockIdx.x < 98) {
        __shared__ float sm[256];
        float v = 0.f;
        for (int i = blockIdx.x * 256 + threadIdx.x; i < 128 * 28 * 28; i += 98 * 256)
            v = fmaxf(v, fabsf(img[i]));
        sm[threadIdx.x] = v;
        __syncthreads();
        for (int s = 128; s > 0; s >>= 1) {
            if (threadIdx.x < s) sm[threadIdx.x] = fmaxf(sm[threadIdx.x], sm[threadIdx.x + s]);
            __syncthreads();
        }
        if (threadIdx.x == 0)
            atomicMax((unsigned int*)(ws + WS_MAX), __float_as_uint(sm[0]));
        return;
    }
    int i = (blockIdx.x - 98) * 256 + threadIdx.x;
    __bf16* Cb = (__bf16*)(ws + WS_CONN);
    const int NCE = MT * 160;              // 23040 (m,k) pairs
    if (i < NCE) {
        int m = i / 160, k = i % 160;
        float vr = 0.f, vi = 0.f;
        if (m < 131 && k < 131) {
            float a = cr[k * 131 + m], b = ci[k * 131 + m];
            float ph = phase[m];
            float cp = cosf(ph), sp = sinf(ph);
            vr = a * cp - b * sp;
            vi = a * sp + b * cp;
        }
        int ca = ((k >> 3) * MT + m) * 8 + (k & 7);    // chunked addr
        Cb[ca]       = (__bf16)vr;
        Cb[NCE + ca] = (__bf16)vi;
    } else if (i < NCE + MT) {
        int j = i - NCE;
        float g = 0.f;
        if (j < 131) {
            float x = gain[j];
            g = (x > 20.f) ? x : log1pf(expf(x));  // softplus
        }
        ws[WS_GSP + j] = g * -0.72134754543f;       // -2*log2(e)*g / 4
    }
}

static __device__ __forceinline__ f32x4 MF(bf16x8 a, bf16x8 b, f32x4 c) {
    return __builtin_amdgcn_mfma_f32_16x16x32_bf16(a, b, c, 0, 0, 0);
}
static __device__ __forceinline__ bf16x8 bneg(bf16x8 a) {
    short8 t = __builtin_bit_cast(short8, a) ^ (short8)(short)0x8000;
    return __builtin_bit_cast(bf16x8, t);
}

// one complex 16x16 tile accumulation; order identical to R17..R31.
#define CPAIR(AR, AI, BR, BI, BNI, P)                                  \
    accr[P] = MF(AR, BR,  accr[P]);                                    \
    accr[P] = MF(AI, BNI, accr[P]);                                    \
    acci[P] = MF(AR, BI,  acci[P]);                                    \
    acci[P] = MF(AI, BR,  acci[P]);

__global__ __launch_bounds__(576, 2)
void k_main(const float* __restrict__ img, const float* __restrict__ ws,
            float* __restrict__ energy) {
    __shared__ __bf16 CrL[17 * MT * 8];            // 39,168 B (17 chunks)
    __shared__ __bf16 CiL[17 * MT * 8];            // 39,168 B
    __shared__ __bf16 OBP[2][9][17 * 16 * 8];      // 78,336 B  [r/i][wave][...]
    __shared__ float  gspL[144];                   // 576 B
    // total 157,248 B -> 1 block/CU, 9 waves (2-3 per SIMD).

    const int tid  = threadIdx.x;
    const int lane = tid & 63;
    const int ln15 = lane & 15;
    const int quad = lane >> 4;
    const int w    = __builtin_amdgcn_readfirstlane(tid >> 6);  // 0..8

    __bf16* __restrict__ OWr = &OBP[0][w][0];
    __bf16* __restrict__ OWi = &OBP[1][w][0];

    // injection scaling (identical rounding chain to R20..R31)
    const float mx = ws[WS_MAX];
    const float sc = (mx > 1e-8f) ? (1.02f / mx) : 1.02f;   // 0.85*4*0.3

    // stage conn chunks 0..16 + gsp -> LDS (the ONLY barrier in the kernel)
    {
        const int4* srcR = (const int4*)(ws + WS_CONN);
        const int4* srcI = (const int4*)(ws + WS_CONN + (MT * 160 / 2));
        int4* dstR = (int4*)CrL;
        int4* dstI = (int4*)CiL;
        for (int i = tid; i < 2448; i += 576) { dstR[i] = srcR[i]; dstI[i] = srcI[i]; }
        if (tid < 144) gspL[tid] = ws[WS_GSP + tid];
    }
    __syncthreads();                                // conn + gsp staged

    const bf16x8 zf = __builtin_bit_cast(bf16x8, (short8)(short)0);

    // ---- wave-task loop: T -> (u = T>>7 in 0..32, im = T&127).
    // 2304 workers (256 blk x 9 waves): r=0 full 2304, r=1 tasks 2304..4223.
#pragma unroll 1
    for (int r = 0; r < 2; ++r) {
        const int T = r * 2304 + blockIdx.x * 9 + w;
        if (T >= NTASK) break;                      // wave-uniform
        const int u  = T >> 7;                      // unique l (0..32)
        const int im = T & 127;
        const float wl  = 1.0f - fabsf((float)u - 32.0f) * (1.0f / 64.0f);
        const float wgt = (u == 0 || u == 32) ? 1.0f : 2.0f;  // mirror count
        const int imgb = im * 784 + (ln15 >> 2) * 28 + (ln15 & 3);

        f32x4 accr[9], acci[9];                     // p = mt
#pragma unroll
        for (int p = 0; p < 9; ++p) { accr[p] = (f32x4)0.f; acci[p] = (f32x4)0.f; }

        // injection: rows j<49 (tiles 0..3)
        auto inj_add = [&]() {
#pragma unroll
            for (int mt = 0; mt < 4; ++mt) {
#pragma unroll
                for (int rr = 0; rr < 4; ++rr) {
                    int j = mt * 16 + quad * 4 + rr;
                    if (j < 49) {
                        int pi = j / 7, pj = j % 7;
                        float px = img[imgb + pi * 112 + pj * 4];
                        float t  = px * sc;
                        accr[mt][rr] = fmaf(t, wl, accr[mt][rr]);
                    }
                }
            }
        };

        // epilogue: out = a * tanh(g*|f|)/|f| (0.25 folded), write own OB.
        // Chunk-17 cells (mt==8, quad>=2: rows 136..143) are exact zeros
        // and are no longer stored — skip the write.
        auto epilogue = [&]() {
#pragma unroll
            for (int mt = 0; mt < 9; ++mt) {
                f32x4 g2v = *(const f32x4*)(gspL + mt * 16 + quad * 4);
                bf16x4 pr, pi;
#pragma unroll
                for (int rr = 0; rr < 4; ++rr) {
                    float ar = accr[mt][rr], ai = acci[mt][rr];
                    float mag2 = fmaf(ar, ar, fmaf(ai, ai, 1.6e-7f));
                    float rsq  = __builtin_amdgcn_rsqf(mag2);
                    float e    = __builtin_amdgcn_exp2f(g2v[rr] * (mag2 * rsq));
                    float uu   = __builtin_amdgcn_rcpf(1.0f + e);
                    float th   = fmaf(-2.0f, e * uu, 1.0f);
                    float scv  = th * rsq;
                    pr[rr] = (__bf16)(ar * scv); pi[rr] = (__bf16)(ai * scv);
                }
                if (mt < 8 || (quad >> 1) == 0) {
                    const int off = ((mt * 2 + (quad >> 1)) * 16 + ln15) * 8
                                  + (quad & 1) * 4;
                    *(bf16x4*)(OWr + off) = pr;
                    *(bf16x4*)(OWi + off) = pi;
                }
            }
        };

        // kt = 4 (k 128..159): only quad 0 (chunk 16) has nonzero data;
        // quads 1..3 (k >= 136) use register zeros — identical operand
        // values to the old chunk-17 LDS zeros -> bit-exact.
        auto kt4_mfma = [&](bool full) {
            bf16x8 br = zf, bi = zf, a7r = zf, a7i = zf, a8r = zf, a8i = zf;
            bf16x8 ar[7], ai[7];
#pragma unroll
            for (int mt = 0; mt < 7; ++mt) { ar[mt] = zf; ai[mt] = zf; }
            if (quad == 0) {
                const int bb = (16 * 16 + ln15) * 8;
                br = *(const bf16x8*)(OWr + bb);
                bi = *(const bf16x8*)(OWi + bb);
                const int ab = (16 * MT + ln15) * 8;
                if (full) {
#pragma unroll
                    for (int mt = 0; mt < 7; ++mt) {
                        ar[mt] = *(const bf16x8*)(CrL + ab + mt * 128);
                        ai[mt] = *(const bf16x8*)(CiL + ab + mt * 128);
                    }
                }
                a7r = *(const bf16x8*)(CrL + ab + 7 * 128);
                a7i = *(const bf16x8*)(CiL + ab + 7 * 128);
                a8r = *(const bf16x8*)(CrL + ab + 8 * 128);
                a8i = *(const bf16x8*)(CiL + ab + 8 * 128);
            }
            bf16x8 bn = bneg(bi);
            if (full) {
#pragma unroll
                for (int mt = 0; mt < 7; ++mt) {
                    CPAIR(ar[mt], ai[mt], br, bi, bn, mt)
                }
            }
            CPAIR(a7r, a7i, br, bi, bn, 7)
            CPAIR(a8r, a8i, br, bi, bn, 8)
        };

        inj_add();                                  // t = 0 (out is zero)
        epilogue();                                 // wave-private, no barrier

        // ---- time loop: zero barriers; burst kt body (R30-identical) ----
#pragma unroll 1
        for (int t = 1; t < NSTEPS - 1; ++t) {
#pragma unroll
            for (int p = 0; p < 9; ++p) { accr[p] *= 0.85f; acci[p] *= 0.85f; }
            if (t < INJ_ST) inj_add();

            // t=1: out(0) rows >=49 exactly zero -> kt 0,1 only.
            const int ktEnd = (t == 1) ? 2 : 4;
#pragma unroll 1
            for (int kt = 0; kt < ktEnd; ++kt) {
                const int rk = kt * 4 + quad;       // <= 15: no remap needed
                // ---- load burst: 2 B + 18 A reads, then MFMA block ----
                const int bb = (rk * 16 + ln15) * 8;
                bf16x8 br = *(const bf16x8*)(OWr + bb);
                bf16x8 bi = *(const bf16x8*)(OWi + bb);
                const int ab = (rk * MT + ln15) * 8;
                bf16x8 ar[9], ai[9];
#pragma unroll
                for (int mt = 0; mt < 9; ++mt) {
                    ar[mt] = *(const bf16x8*)(CrL + ab + mt * 128);
                    ai[mt] = *(const bf16x8*)(CiL + ab + mt * 128);
                }
                bf16x8 bn = bneg(bi);
#pragma unroll
                for (int mt = 0; mt < 9; ++mt) {
                    CPAIR(ar[mt], ai[mt], br, bi, bn, mt)
                }
            }
            if (t > 1) kt4_mfma(true);              // kt 4 (quad0-only data)
            epilogue();                             // wave-private, no barrier
        }

        // ---- t = 9: only rows 121..130 (tiles 7,8) feed energy ----
        accr[7] *= 0.85f; acci[7] *= 0.85f;
        accr[8] *= 0.85f; acci[8] *= 0.85f;
#pragma unroll 1
        for (int kt = 0; kt < 4; ++kt) {
            const int rk = kt * 4 + quad;
            const int bb = (rk * 16 + ln15) * 8;
            bf16x8 br = *(const bf16x8*)(OWr + bb);
            bf16x8 bi = *(const bf16x8*)(OWi + bb);
            const int ab = (rk * MT + ln15) * 8;
            bf16x8 ar7 = *(const bf16x8*)(CrL + ab + 7 * 128);
            bf16x8 ai7 = *(const bf16x8*)(CiL + ab + 7 * 128);
            bf16x8 ar8 = *(const bf16x8*)(CrL + ab + 8 * 128);
            bf16x8 ai8 = *(const bf16x8*)(CiL + ab + 8 * 128);
            bf16x8 bn = bneg(bi);
            CPAIR(ar7, ai7, br, bi, bn, 7)
            CPAIR(ar8, ai8, br, bi, bn, 8)
        }
        kt4_mfma(false);                            // kt 4, tiles 7,8 only

        // ---- energy: per-lane |out|^2, quad shfl-reduce over 16 cols,
        // one atomicAdd per (j), weighted by mirror multiplicity ----
#pragma unroll
        for (int mt = 7; mt < 9; ++mt) {
#pragma unroll
            for (int rr = 0; rr < 4; ++rr) {
                int j = mt * 16 + quad * 4 + rr;
                if (j >= 121 && j <= 130) {
                    float ar = accr[mt][rr], ai = acci[mt][rr];
                    float mag2 = fmaf(ar, ar, fmaf(ai, ai, 1.6e-7f));
                    float rsq  = __builtin_amdgcn_rsqf(mag2);
                    float e    = __builtin_amdgcn_exp2f(gspL[j] * (mag2 * rsq));
                    float uu   = __builtin_amdgcn_rcpf(1.0f + e);
                    float th   = fmaf(-2.0f, e * uu, 1.0f);
                    float scv  = th * rsq;
                    float orv = ar * scv, oiv = ai * scv;
                    float e2 = orv * orv + oiv * oiv;
                    e2 += __shfl_xor(e2, 1);
                    e2 += __shfl_xor(e2, 2);
                    e2 += __shfl_xor(e2, 4);
                    e2 += __shfl_xor(e2, 8);
                    if (ln15 == 0)
                        atomicAdd(energy + im * 10 + (j - 121), e2 * wgt);
                }
            }
        }
    }
}

__global__ void k_readout(const float* __restrict__ ws,
                          const float* __restrict__ W,
                          const float* __restrict__ bias,
                          float* __restrict__ out) {
    int i = blockIdx.x * 256 + threadIdx.x;
    if (i < 1280) {
        int b = i / 10, o = i % 10;
        float s = bias[o];
#pragma unroll
        for (int f = 0; f < 10; ++f) {
            float feat = log1pf(ws[WS_ENERGY + b * 10 + f] + 1e-8f);
            s = fmaf(feat, W[o * 10 + f], s);
        }
        out[i] = s;
    }
}

extern "C" void kernel_launch(void* const* d_in, const int* in_sizes, int n_in,
                              void* d_out, int out_size, void* d_ws, size_t ws_size,
                              hipStream_t stream) {
    const float* images = (const float*)d_in[0];
    const float* conn_r = (const float*)d_in[1];
    const float* conn_i = (const float*)d_in[2];
    const float* phase  = (const float*)d_in[3];
    const float* gain   = (const float*)d_in[4];
    const float* W      = (const float*)d_in[5];
    const float* bias   = (const float*)d_in[6];
    float* ws  = (float*)d_ws;
    float* out = (float*)d_out;

    // zero WS_MAX + energy (floats 0..1343) — stream-ordered, capture-safe
    hipMemsetAsync(ws, 0, (WS_ENERGY + 1280) * sizeof(float), stream);
    hipLaunchKernelGGL(k_pre, dim3(189), dim3(256), 0, stream,
                       images, conn_r, conn_i, phase, gain, ws);
    hipLaunchKernelGGL(k_main, dim3(256), dim3(576), 0, stream,
                       images, ws, ws + WS_ENERGY);
    hipLaunchKernelGGL(k_readout, dim3(5), dim3(256), 0, stream, ws, W, bias, out);
}

// Round 16
// 188.255 us; speedup vs baseline: 1.3809x; 1.3809x over previous
//
#include <hip/hip_runtime.h>
#include <cmath>

// PhaseAwareClassifier on MI355X — R33: R30 (verbatim body) + solo-wave
// tail round.
// R32 post-mortem: 9-wave/576-thr geometry spilled (FETCH/WRITE 73/70MB at
// VGPR_Count 84 — allocator budgeted for >2 waves/SIMD, silently spilled
// the kt burst) -> 199us. Non-power-of-2 wave counts join the allocator
// hazard list (R19/R24/R26/R27/R32). FULL revert to R30's proven body
// (157.9us, VGPR 92 clean).
// Remaining waste is the TAIL: R30 round 3 = 128 tasks on 16 blocks x 8
// waves (240 CUs idle for 1/3 of the kernel). Fix without touching block
// geometry: spread the 128 leftover tasks as ONE task to wave 0 of blocks
// 0..127. Solo wave per CU: whole LDS unit + SIMD to itself, est ~11us
// (vs 52.6us for an 8-way-shared round). Waves 1..7 just exit. Same tasks,
// same math; only energy-atomic order changes (already nondeterministic).
// absmax 0.0078125 expected bit-identical.
// LDS: conn 82,944 + OBP 73,728 + gsp 576 = 157,248 B -> 1 block/CU.

#define NSTEPS  10
#define INJ_ST  4
#define MT      144          // padded M (9 tiles of 16)
#define NTASK   4224         // 33 unique l x 128 images

typedef __bf16 bf16x8 __attribute__((ext_vector_type(8)));
typedef __bf16 bf16x4 __attribute__((ext_vector_type(4)));
typedef short  short8 __attribute__((ext_vector_type(8)));
typedef float  f32x4  __attribute__((ext_vector_type(4)));

// workspace layout (float offsets)
#define WS_MAX    0          // 1      enc_max (uint-ordered float)
#define WS_ENERGY 64         // 1280   energy[b][10]
#define WS_GSP    2048       // 144    g2q[j] = -0.5*log2(e)*softplus(gain)
#define WS_CONN   4096       // 2 bf16 mats [20][144][8] chunked: Cr, Ci

// fused prep: blocks 0..97 = image absmax; blocks 98.. = conn + gsp tables
__global__ void k_pre(const float* __restrict__ img,
                      const float* __restrict__ cr, const float* __restrict__ ci,
                      const float* __restrict__ phase, const float* __restrict__ gain,
                      float* ws) {
    if (blockIdx.x < 98) {
        __shared__ float sm[256];
        float v = 0.f;
        for (int i = blockIdx.x * 256 + threadIdx.x; i < 128 * 28 * 28; i += 98 * 256)
            v = fmaxf(v, fabsf(img[i]));
        sm[threadIdx.x] = v;
        __syncthreads();
        for (int s = 128; s > 0; s >>= 1) {
            if (threadIdx.x < s) sm[threadIdx.x] = fmaxf(sm[threadIdx.x], sm[threadIdx.x + s]);
            __syncthreads();
        }
        if (threadIdx.x == 0)
            atomicMax((unsigned int*)(ws + WS_MAX), __float_as_uint(sm[0]));
        return;
    }
    int i = (blockIdx.x - 98) * 256 + threadIdx.x;
    __bf16* Cb = (__bf16*)(ws + WS_CONN);
    const int NCE = MT * 160;              // 23040 (m,k) pairs
    if (i < NCE) {
        int m = i / 160, k = i % 160;
        float vr = 0.f, vi = 0.f;
        if (m < 131 && k < 131) {
            float a = cr[k * 131 + m], b = ci[k * 131 + m];
            float ph = phase[m];
            float cp = cosf(ph), sp = sinf(ph);
            vr = a * cp - b * sp;
            vi = a * sp + b * cp;
        }
        int ca = ((k >> 3) * MT + m) * 8 + (k & 7);    // chunked addr
        Cb[ca]       = (__bf16)vr;
        Cb[NCE + ca] = (__bf16)vi;
    } else if (i < NCE + MT) {
        int j = i - NCE;
        float g = 0.f;
        if (j < 131) {
            float x = gain[j];
            g = (x > 20.f) ? x : log1pf(expf(x));  // softplus
        }
        ws[WS_GSP + j] = g * -0.72134754543f;       // -2*log2(e)*g / 4
    }
}

static __device__ __forceinline__ f32x4 MF(bf16x8 a, bf16x8 b, f32x4 c) {
    return __builtin_amdgcn_mfma_f32_16x16x32_bf16(a, b, c, 0, 0, 0);
}
static __device__ __forceinline__ bf16x8 bneg(bf16x8 a) {
    short8 t = __builtin_bit_cast(short8, a) ^ (short8)(short)0x8000;
    return __builtin_bit_cast(bf16x8, t);
}

// one complex 16x16 tile accumulation; order identical to R17..R32.
#define CPAIR(AR, AI, BR, BI, BNI, P)                                  \
    accr[P] = MF(AR, BR,  accr[P]);                                    \
    accr[P] = MF(AI, BNI, accr[P]);                                    \
    acci[P] = MF(AR, BI,  acci[P]);                                    \
    acci[P] = MF(AI, BR,  acci[P]);

__global__ __launch_bounds__(512, 2)
void k_main(const float* __restrict__ img, const float* __restrict__ ws,
            float* __restrict__ energy) {
    __shared__ __bf16 CrL[18 * MT * 8];            // 41,472 B
    __shared__ __bf16 CiL[18 * MT * 8];            // 41,472 B
    __shared__ __bf16 OBP[2][8][18 * 16 * 8];      // 73,728 B  [r/i][wave][...]
    __shared__ float  gspL[144];                   // 576 B
    // total 157,248 B -> 1 block/CU, 8 waves = 2/SIMD (hint matches).

    const int tid  = threadIdx.x;
    const int lane = tid & 63;
    const int ln15 = lane & 15;
    const int quad = lane >> 4;
    const int w    = __builtin_amdgcn_readfirstlane(tid >> 6);  // 0..7

    __bf16* __restrict__ OWr = &OBP[0][w][0];
    __bf16* __restrict__ OWi = &OBP[1][w][0];

    // injection scaling (identical rounding chain to R20..R32)
    const float mx = ws[WS_MAX];
    const float sc = (mx > 1e-8f) ? (1.02f / mx) : 1.02f;   // 0.85*4*0.3

    // stage conn chunks 0..17 + gsp -> LDS (the ONLY barrier in the kernel)
    {
        const int4* srcR = (const int4*)(ws + WS_CONN);
        const int4* srcI = (const int4*)(ws + WS_CONN + (MT * 160 / 2));
        int4* dstR = (int4*)CrL;
        int4* dstI = (int4*)CiL;
        for (int i = tid; i < 2592; i += 512) { dstR[i] = srcR[i]; dstI[i] = srcI[i]; }
        if (tid < 144) gspL[tid] = ws[WS_GSP + tid];
    }
    __syncthreads();                                // conn + gsp staged

    // ---- wave-task loop: T -> (u = T>>7 in 0..32, im = T&127).
    // r=0,1: all 2048 workers. r=2: the 128 leftover tasks go to wave 0 of
    // blocks 0..127 (solo wave per CU -> ~11us, vs 52.6us on 16 blocks).
#pragma unroll 1
    for (int r = 0; r < 3; ++r) {
        int T;
        if (r < 2) {
            T = r * 2048 + blockIdx.x * 8 + w;
        } else {
            if (w != 0 || blockIdx.x >= 128) break; // wave-uniform exit
            T = 4096 + blockIdx.x;
        }
        if (T >= NTASK) break;                      // wave-uniform
        const int u  = T >> 7;                      // unique l (0..32)
        const int im = T & 127;
        const float wl  = 1.0f - fabsf((float)u - 32.0f) * (1.0f / 64.0f);
        const float wgt = (u == 0 || u == 32) ? 1.0f : 2.0f;  // mirror count
        const int imgb = im * 784 + (ln15 >> 2) * 28 + (ln15 & 3);

        f32x4 accr[9], acci[9];                     // p = mt
#pragma unroll
        for (int p = 0; p < 9; ++p) { accr[p] = (f32x4)0.f; acci[p] = (f32x4)0.f; }

        // injection: rows j<49 (tiles 0..3)
        auto inj_add = [&]() {
#pragma unroll
            for (int mt = 0; mt < 4; ++mt) {
#pragma unroll
                for (int rr = 0; rr < 4; ++rr) {
                    int j = mt * 16 + quad * 4 + rr;
                    if (j < 49) {
                        int pi = j / 7, pj = j % 7;
                        float px = img[imgb + pi * 112 + pj * 4];
                        float t  = px * sc;
                        accr[mt][rr] = fmaf(t, wl, accr[mt][rr]);
                    }
                }
            }
        };

        // epilogue: out = a * tanh(g*|f|)/|f| (0.25 folded), write own OB
        auto epilogue = [&]() {
#pragma unroll
            for (int mt = 0; mt < 9; ++mt) {
                f32x4 g2v = *(const f32x4*)(gspL + mt * 16 + quad * 4);
                bf16x4 pr, pi;
#pragma unroll
                for (int rr = 0; rr < 4; ++rr) {
                    float ar = accr[mt][rr], ai = acci[mt][rr];
                    float mag2 = fmaf(ar, ar, fmaf(ai, ai, 1.6e-7f));
                    float rsq  = __builtin_amdgcn_rsqf(mag2);
                    float e    = __builtin_amdgcn_exp2f(g2v[rr] * (mag2 * rsq));
                    float uu   = __builtin_amdgcn_rcpf(1.0f + e);
                    float th   = fmaf(-2.0f, e * uu, 1.0f);
                    float scv  = th * rsq;
                    pr[rr] = (__bf16)(ar * scv); pi[rr] = (__bf16)(ai * scv);
                }
                const int off = ((mt * 2 + (quad >> 1)) * 16 + ln15) * 8
                              + (quad & 1) * 4;
                *(bf16x4*)(OWr + off) = pr;
                *(bf16x4*)(OWi + off) = pi;
            }
        };

        inj_add();                                  // t = 0 (out is zero)
        epilogue();                                 // wave-private, no barrier

        // ---- time loop: zero barriers; burst kt body (R30-identical) ----
#pragma unroll 1
        for (int t = 1; t < NSTEPS - 1; ++t) {
#pragma unroll
            for (int p = 0; p < 9; ++p) { accr[p] *= 0.85f; acci[p] *= 0.85f; }
            if (t < INJ_ST) inj_add();

            // t=1: out(0) rows >=49 exactly zero -> kt 0,1 only.
            const int ktEnd = (t == 1) ? 2 : 5;
            // kch 18,19 remap to chunk 17 (zeros both sides). unroll(1): R15.
#pragma unroll 1
            for (int kt = 0; kt < ktEnd; ++kt) {
                const int kch = kt * 4 + quad;
                const int rk  = (kch > 17) ? 17 : kch;
                // ---- load burst: 2 B + 18 A reads, then MFMA block ----
                const int bb  = (rk * 16 + ln15) * 8;
                bf16x8 br = *(const bf16x8*)(OWr + bb);
                bf16x8 bi = *(const bf16x8*)(OWi + bb);
                const int ab = (rk * MT + ln15) * 8;
                bf16x8 ar[9], ai[9];
#pragma unroll
                for (int mt = 0; mt < 9; ++mt) {
                    ar[mt] = *(const bf16x8*)(CrL + ab + mt * 128);
                    ai[mt] = *(const bf16x8*)(CiL + ab + mt * 128);
                }
                bf16x8 bn = bneg(bi);
#pragma unroll
                for (int mt = 0; mt < 9; ++mt) {
                    CPAIR(ar[mt], ai[mt], br, bi, bn, mt)
                }
            }
            epilogue();                             // wave-private, no barrier
        }

        // ---- t = 9: only rows 121..130 (tiles 7,8) feed energy ----
        accr[7] *= 0.85f; acci[7] *= 0.85f;
        accr[8] *= 0.85f; acci[8] *= 0.85f;
#pragma unroll 1
        for (int kt = 0; kt < 5; ++kt) {
            const int kch = kt * 4 + quad;
            const int rk  = (kch > 17) ? 17 : kch;
            const int bb  = (rk * 16 + ln15) * 8;
            bf16x8 br = *(const bf16x8*)(OWr + bb);
            bf16x8 bi = *(const bf16x8*)(OWi + bb);
            const int ab = (rk * MT + ln15) * 8;
            bf16x8 ar7 = *(const bf16x8*)(CrL + ab + 7 * 128);
            bf16x8 ai7 = *(const bf16x8*)(CiL + ab + 7 * 128);
            bf16x8 ar8 = *(const bf16x8*)(CrL + ab + 8 * 128);
            bf16x8 ai8 = *(const bf16x8*)(CiL + ab + 8 * 128);
            bf16x8 bn = bneg(bi);
            CPAIR(ar7, ai7, br, bi, bn, 7)
            CPAIR(ar8, ai8, br, bi, bn, 8)
        }

        // ---- energy: per-lane |out|^2, quad shfl-reduce over 16 cols,
        // one atomicAdd per (j), weighted by mirror multiplicity ----
#pragma unroll
        for (int mt = 7; mt < 9; ++mt) {
#pragma unroll
            for (int rr = 0; rr < 4; ++rr) {
                int j = mt * 16 + quad * 4 + rr;
                if (j >= 121 && j <= 130) {
                    float ar = accr[mt][rr], ai = acci[mt][rr];
                    float mag2 = fmaf(ar, ar, fmaf(ai, ai, 1.6e-7f));
                    float rsq  = __builtin_amdgcn_rsqf(mag2);
                    float e    = __builtin_amdgcn_exp2f(gspL[j] * (mag2 * rsq));
                    float uu   = __builtin_amdgcn_rcpf(1.0f + e);
                    float th   = fmaf(-2.0f, e * uu, 1.0f);
                    float scv  = th * rsq;
                    float orv = ar * scv, oiv = ai * scv;
                    float e2 = orv * orv + oiv * oiv;
                    e2 += __shfl_xor(e2, 1);
                    e2 += __shfl_xor(e2, 2);
                    e2 += __shfl_xor(e2, 4);
                    e2 += __shfl_xor(e2, 8);
                    if (ln15 == 0)
                        atomicAdd(energy + im * 10 + (j - 121), e2 * wgt);
                }
            }
        }
    }
}

__global__ void k_readout(const float* __restrict__ ws,
                          const float* __restrict__ W,
                          const float* __restrict__ bias,
                          float* __restrict__ out) {
    int i = blockIdx.x * 256 + threadIdx.x;
    if (i < 1280) {
        int b = i / 10, o = i % 10;
        float s = bias[o];
#pragma unroll
        for (int f = 0; f < 10; ++f) {
            float feat = log1pf(ws[WS_ENERGY + b * 10 + f] + 1e-8f);
            s = fmaf(feat, W[o * 10 + f], s);
        }
        out[i] = s;
    }
}

extern "C" void kernel_launch(void* const* d_in, const int* in_sizes, int n_in,
                              void* d_out, int out_size, void* d_ws, size_t ws_size,
                              hipStream_t stream) {
    const float* images = (const float*)d_in[0];
    const float* conn_r = (const float*)d_in[1];
    const float* conn_i = (const float*)d_in[2];
    const float* phase  = (const float*)d_in[3];
    const float* gain   = (const float*)d_in[4];
    const float* W      = (const float*)d_in[5];
    const float* bias   = (const float*)d_in[6];
    float* ws  = (float*)d_ws;
    float* out = (float*)d_out;

    // zero WS_MAX + energy (floats 0..1343) — stream-ordered, capture-safe
    hipMemsetAsync(ws, 0, (WS_ENERGY + 1280) * sizeof(float), stream);
    hipLaunchKernelGGL(k_pre, dim3(189), dim3(256), 0, stream,
                       images, conn_r, conn_i, phase, gain, ws);
    hipLaunchKernelGGL(k_main, dim3(256), dim3(512), 0, stream,
                       images, ws, ws + WS_ENERGY);
    hipLaunchKernelGGL(k_readout, dim3(5), dim3(256), 0, stream, ws, W, bias, out);
}